// Round 8
// baseline (251.862 us; speedup 1.0000x reference)
//
#include <hip/hip_runtime.h>
#include <hip/hip_bf16.h>

// GCN: 2x GCNConv(128->128) + LeakyReLU(0.1) + mean over channels.
// N=50000, E=1600000, D=128, fp32 in/out.
//
// R8: XCD-pinned channel-quartered gather. Evidence R2/R4/R6/R7: gather is
//     pinned at 3.3-3.7 TB/s of TCC FETCH regardless of MLP/VALU -> bound by
//     L2-miss service rate on random 64B lines. Fix: quarter-major g-table
//     (4 x 3.2MB, one 64B line per quarter-row); blockIdx%8 slot -> XCD
//     round-robin; quarter = slot>>1 => each XCD gathers from ONE quarter
//     that fits its 4MB L2. esrc via nontemporal loads (no table eviction).
//     R5 failed this idea with serial passes + no pinning (working set 6.6MB).
// CSR build: R6 atomic-free bucket sort. GEMM: R7 MFMA bf16 (epilogue now
// writes quarter-major). Math (verified R2-R7):
//   g[u]=dinv[u]*(x@W1)[u]  (bf16-packed);
//   mg[u]=dinv[u]*dot(lrelu(dinv[u]*(g[u]+sum g[nbr]) + b1), mean_j W2[:,j]);
//   out[v]=dinv[v]*(mg[v]+sum mg[nbr]) + mean(b2).

#define N_NODES 50000
#define NPAD 50048
#define D 128
#define BK 196           // node buckets: v>>8
#define CHUNK 4096       // edges per stage-1 block

typedef unsigned int uint;
typedef unsigned short u16;
typedef __attribute__((ext_vector_type(8))) short short8;   // 8 bf16 (4 VGPRs)
typedef __attribute__((ext_vector_type(4))) float floatx4;

__device__ __forceinline__ u16 cvt_bf16(float f) {
    uint u = __float_as_uint(f);
    return (u16)((u + 0x7fffu + ((u >> 16) & 1u)) >> 16);   // RNE
}
__device__ __forceinline__ uint pack_bf2(float a, float b) {
    return (uint)cvt_bf16(a) | ((uint)cvt_bf16(b) << 16);
}

// ---------------- stage 1: per-chunk bucket histogram (LDS atomics) ----------------
__global__ void hist_kernel(const int* __restrict__ dst, uint* __restrict__ H, int E, int CHN) {
    __shared__ uint h[BK];
    int t = threadIdx.x, c = blockIdx.x;
    if (t < BK) h[t] = 0;
    __syncthreads();
    int e0 = c * CHUNK;
    for (int i = t; i < CHUNK; i += 256) {
        int e = e0 + i;
        if (e < E) atomicAdd(&h[dst[e] >> 8], 1u);
    }
    __syncthreads();
    if (t < BK) H[t * CHN + c] = h[t];     // bucket-major for column scan
}

// per-bucket exclusive scan over chunks (in place); totals -> T
__global__ void colscan_kernel(uint* __restrict__ H, uint* __restrict__ T, int CHN) {
    __shared__ uint s[256];
    int t = threadIdx.x, b = blockIdx.x;
    uint carry = 0;
    for (int base = 0; base < CHN; base += 256) {
        int idx = base + t;
        uint v = (idx < CHN) ? H[b * CHN + idx] : 0u;
        s[t] = v;
        __syncthreads();
#pragma unroll
        for (int off = 1; off < 256; off <<= 1) {
            uint u = (t >= off) ? s[t - off] : 0u;
            __syncthreads();
            s[t] += u;
            __syncthreads();
        }
        if (idx < CHN) H[b * CHN + idx] = carry + s[t] - v;   // exclusive + carry
        carry += s[255];
        __syncthreads();
    }
    if (t == 0) T[b] = carry;
}

// exclusive scan of bucket totals -> B[0..BK]; row[N]=E
__global__ void totscan_kernel(const uint* __restrict__ T, uint* __restrict__ B,
                               int* __restrict__ row, int E, int N) {
    __shared__ uint s[256];
    int t = threadIdx.x;
    uint v = (t < BK) ? T[t] : 0u;
    s[t] = v;
    __syncthreads();
#pragma unroll
    for (int off = 1; off < 256; off <<= 1) {
        uint u = (t >= off) ? s[t - off] : 0u;
        __syncthreads();
        s[t] += u;
        __syncthreads();
    }
    if (t < BK) B[t] = s[t] - v;
    if (t == 0) { B[BK] = (uint)E; row[N] = E; }
}

// scatter edges into bucket regions (LDS cursors)
__global__ void scatter_kernel(const int* __restrict__ src, const int* __restrict__ dst,
                               const uint* __restrict__ H, const uint* __restrict__ B,
                               uint* __restrict__ EB, int E, int CHN) {
    __shared__ uint cur[BK];
    int t = threadIdx.x, c = blockIdx.x;
    if (t < BK) cur[t] = B[t] + H[t * CHN + c];
    __syncthreads();
    int e0 = c * CHUNK;
    for (int i = t; i < CHUNK; i += 256) {
        int e = e0 + i;
        if (e < E) {
            int d = dst[e];
            uint slot = atomicAdd(&cur[d >> 8], 1u);
            EB[slot] = ((uint)(d & 255) << 16) | (uint)src[e];
        }
    }
}

// stage 2: per-bucket counting sort by dst&255 -> esrc, row, dinv (dense writes)
__global__ void bucket_sort_kernel(const uint* __restrict__ EB, const uint* __restrict__ B,
                                   int* __restrict__ row, float* __restrict__ dinv,
                                   u16* __restrict__ esrc, int N) {
    __shared__ uint cnt[256], s[256], cur[256];
    int t = threadIdx.x, b = blockIdx.x;
    uint base = B[b], ne = B[b + 1] - base;
    cnt[t] = 0;
    __syncthreads();
    for (uint i = t; i < ne; i += 256) atomicAdd(&cnt[EB[base + i] >> 16], 1u);
    __syncthreads();
    uint c = cnt[t];
    s[t] = c;
    __syncthreads();
#pragma unroll
    for (int off = 1; off < 256; off <<= 1) {
        uint u = (t >= off) ? s[t - off] : 0u;
        __syncthreads();
        s[t] += u;
        __syncthreads();
    }
    uint p = s[t] - c;                      // exclusive prefix within bucket
    int v = (b << 8) + t;
    if (v < N) {
        row[v] = (int)(base + p);
        dinv[v] = rsqrtf((float)(c + 1u));  // +1 self-loop
    }
    cur[t] = base + p;
    __syncthreads();
    for (uint i = t; i < ne; i += 256) {
        uint u = EB[base + i];
        uint slot = atomicAdd(&cur[u >> 16], 1u);
        esrc[slot] = (u16)(u & 0xffffu);
    }
}

// ---------------- w2m[k] = mean_j W2[k,j]; w2m[128] = mean(b2) ----------------
__global__ void w2m_kernel(const float* __restrict__ W2, const float* __restrict__ b2,
                           float* __restrict__ w2m) {
    int k = blockIdx.x, lane = threadIdx.x;   // grid 129 x 64
    const float* p = (k < 128) ? (W2 + k * 128) : b2;
    float s = p[lane] + p[lane + 64];
#pragma unroll
    for (int off = 32; off > 0; off >>= 1) s += __shfl_down(s, off, 64);
    if (lane == 0) w2m[k] = s * (1.0f / 128.0f);
}

// ---------------- MFMA GEMM: quarter-major g16 = bf16( dinv * (x @ W1) ) ----------------
// 4 waves x 16 rows per block; W1^T staged bf16 in LDS (stride 136);
// A-frags from global fp32 + cvt. Epilogue writes quarter-major:
// channel c of row r -> uint index (c>>5)*NPAD*16 + r*16 + ((c&31)>>1).
#define WT_STRIDE 136
__global__ __launch_bounds__(256) void gemm_mfma_kernel(
    const float* __restrict__ A, const float* __restrict__ W,
    uint* __restrict__ G32, const float* __restrict__ dinv, int M) {
    __shared__ u16 Wt[128 * WT_STRIDE];    // 34.8 KB
    int t = threadIdx.x;
    for (int i = t; i < 128 * 128; i += 256) {
        int k = i >> 7, n = i & 127;
        Wt[n * WT_STRIDE + k] = cvt_bf16(W[i]);
    }
    __syncthreads();

    int wave = t >> 6, lane = t & 63;
    int m = lane & 15, quad = lane >> 4;
    int rowa = blockIdx.x * 64 + wave * 16 + m;
    int rowc = rowa < M ? rowa : M - 1;
    const float* Arow = A + (long)rowc * D;

    short8 afrag[4];
#pragma unroll
    for (int kt = 0; kt < 4; kt++) {
        int k0 = kt * 32 + quad * 8;
        float4 f0 = *(const float4*)(Arow + k0);
        float4 f1 = *(const float4*)(Arow + k0 + 4);
        short8 af;
        af[0] = (short)cvt_bf16(f0.x); af[1] = (short)cvt_bf16(f0.y);
        af[2] = (short)cvt_bf16(f0.z); af[3] = (short)cvt_bf16(f0.w);
        af[4] = (short)cvt_bf16(f1.x); af[5] = (short)cvt_bf16(f1.y);
        af[6] = (short)cvt_bf16(f1.z); af[7] = (short)cvt_bf16(f1.w);
        afrag[kt] = af;
    }

    int orow0 = blockIdx.x * 64 + wave * 16;
    float dv[4]; bool ok[4];
#pragma unroll
    for (int r = 0; r < 4; r++) {
        int orow = orow0 + quad * 4 + r;
        ok[r] = orow < M;
        dv[r] = dinv[ok[r] ? orow : (M - 1)];
    }

    for (int n0 = 0; n0 < 128; n0 += 16) {
        floatx4 acc = {0.f, 0.f, 0.f, 0.f};
#pragma unroll
        for (int kt = 0; kt < 4; kt++) {
            short8 bf = *(const short8*)(Wt + (n0 + m) * WT_STRIDE + kt * 32 + quad * 8);
            acc = __builtin_amdgcn_mfma_f32_16x16x32_bf16(afrag[kt], bf, acc, 0, 0, 0);
        }
#pragma unroll
        for (int r = 0; r < 4; r++) {
            float val = acc[r] * dv[r];
            float oth = __shfl_xor(val, 1, 64);          // partner column
            if (ok[r] && (m & 1) == 0) {
                int orow = orow0 + quad * 4 + r;
                int c = n0 + m;
                G32[(long)(c >> 5) * NPAD * 16 + (long)orow * 16 + ((c & 31) >> 1)]
                    = pack_bf2(val, oth);
            }
        }
    }
}

// ---------------- XCD-pinned quarter gather + lrelu + dot(w2m) ----------------
// Grid = N blocks (N%8==0). slot=blockIdx%8 -> XCD (round-robin heuristic);
// quarter q=slot>>1 => each XCD touches ONE 3.2MB quarter table (fits 4MB L2).
// One wave per (node, quarter): 16 chains x 4 lanes x uint4 (64B line/edge).
__global__ __launch_bounds__(256) void gather_q_kernel(
    const int* __restrict__ row, const u16* __restrict__ esrc,
    const uint* __restrict__ g16, const float* __restrict__ dinv,
    const float* __restrict__ b1, const float* __restrict__ w2m,
    float* __restrict__ partial, int N) {
    int b = blockIdx.x;
    int slot = b & 7;
    int q = slot >> 1;
    int wave = threadIdx.x >> 6;
    int lane = threadIdx.x & 63;
    int v = (b >> 3) * 8 + (slot & 1) * 4 + wave;
    if (v >= N) return;
    int chain = lane >> 2, p = lane & 3;   // 16 chains; lane p covers channels q*32+p*8..+7

    const uint4* gq = (const uint4*)(g16 + (long)q * NPAD * 16);   // 4 uint4 per row
    float acc[8];
#pragma unroll
    for (int i = 0; i < 8; i++) acc[i] = 0.f;

#define ACC4(u) {                                                        \
    acc[0] += __uint_as_float((u).x << 16); acc[1] += __uint_as_float((u).x & 0xffff0000u); \
    acc[2] += __uint_as_float((u).y << 16); acc[3] += __uint_as_float((u).y & 0xffff0000u); \
    acc[4] += __uint_as_float((u).z << 16); acc[5] += __uint_as_float((u).z & 0xffff0000u); \
    acc[6] += __uint_as_float((u).w << 16); acc[7] += __uint_as_float((u).w & 0xffff0000u); }

    if (chain == 0) {              // self-loop term
        uint4 u = gq[(long)v * 4 + p];
        ACC4(u)
    }
    int jb = row[v], je = row[v + 1];
    int j = jb + chain;
    if (j < je) {                  // 2-deep pipeline per chain
        int s0 = (int)__builtin_nontemporal_load(&esrc[j]);
        uint4 u0 = gq[(long)s0 * 4 + p];
        j += 16;
        while (j < je) {
            int s1 = (int)__builtin_nontemporal_load(&esrc[j]);
            uint4 u1 = gq[(long)s1 * 4 + p];
            j += 16;
            ACC4(u0)
            u0 = u1;
        }
        ACC4(u0)
    }
#undef ACC4

    // butterfly over the 16 chains: every lane ends with totals for its p-slice
#pragma unroll
    for (int i = 0; i < 8; i++) {
        acc[i] += __shfl_xor(acc[i], 4, 64);
        acc[i] += __shfl_xor(acc[i], 8, 64);
        acc[i] += __shfl_xor(acc[i], 16, 64);
        acc[i] += __shfl_xor(acc[i], 32, 64);
    }

    // epilogue on all lanes (p-dependent), then butterfly over p
    float dvv = dinv[v];
    const float2* bp = (const float2*)b1;
    const float2* wp = (const float2*)w2m;
    float s = 0.f;
#pragma unroll
    for (int k = 0; k < 4; k++) {
        float2 bb = bp[q * 16 + p * 4 + k];
        float2 wm = wp[q * 16 + p * 4 + k];
        float t0 = dvv * acc[2 * k]     + bb.x; t0 = t0 >= 0.f ? t0 : 0.1f * t0;
        float t1 = dvv * acc[2 * k + 1] + bb.y; t1 = t1 >= 0.f ? t1 : 0.1f * t1;
        s += t0 * wm.x + t1 * wm.y;
    }
    s += __shfl_xor(s, 1, 64);
    s += __shfl_xor(s, 2, 64);
    if (lane == 0) partial[q * NPAD + v] = s;
}

// ---------------- mg[v] = dinv[v] * sum_q partial[q][v] ----------------
__global__ void mg_kernel(const float* __restrict__ partial, const float* __restrict__ dinv,
                          float* __restrict__ mg, int N) {
    int v = blockIdx.x * blockDim.x + threadIdx.x;
    if (v >= N) return;
    mg[v] = dinv[v] * (partial[v] + partial[NPAD + v] +
                       partial[2 * NPAD + v] + partial[3 * NPAD + v]);
}

// ---------------- scalar aggregate for conv2 + mean ----------------
__global__ void out_kernel(const int* __restrict__ row, const u16* __restrict__ esrc,
                           const float* __restrict__ mg, const float* __restrict__ dinv,
                           const float* __restrict__ w2m, float* __restrict__ out, int N) {
    int v = blockIdx.x * blockDim.x + threadIdx.x;
    if (v >= N) return;
    float acc = mg[v];
    int jb = row[v], je = row[v + 1];
    int j = jb;
    for (; j + 8 <= je; j += 8) {
        acc += mg[esrc[j]] + mg[esrc[j + 1]] + mg[esrc[j + 2]] + mg[esrc[j + 3]] +
               mg[esrc[j + 4]] + mg[esrc[j + 5]] + mg[esrc[j + 6]] + mg[esrc[j + 7]];
    }
    for (; j < je; j++) acc += mg[esrc[j]];
    out[v] = dinv[v] * acc + w2m[128];
}

extern "C" void kernel_launch(void* const* d_in, const int* in_sizes, int n_in,
                              void* d_out, int out_size, void* d_ws, size_t ws_size,
                              hipStream_t stream) {
    const float* x  = (const float*)d_in[0];
    const int* ei   = (const int*)d_in[1];
    const float* W1 = (const float*)d_in[2];
    const float* b1 = (const float*)d_in[3];
    const float* W2 = (const float*)d_in[4];
    const float* b2 = (const float*)d_in[5];
    float* out = (float*)d_out;

    const int N = N_NODES;
    const int E = in_sizes[1] / 2;
    const int* src = ei;
    const int* dst = ei + E;
    const int CHN = (E + CHUNK - 1) / CHUNK;   // 391
    const int nblocks = (N + 255) / 256;       // 196

    // workspace (4B units). EB aliases g16 (dead before gemm writes g16).
    float*    dinv    = (float*)d_ws;                     // [NPAD]
    int*      row     = (int*)(dinv + NPAD);              // [N+1 -> NPAD+16]
    uint*     B       = (uint*)(row + NPAD + 16);         // [256] (BK+1 used)
    float*    w2m     = (float*)(B + 256);                // [256] ([128]=mean b2)
    float*    mg      = w2m + 256;                        // [NPAD]
    uint*     T       = (uint*)(mg + NPAD);               // [256]
    float*    partial = (float*)(T + 256);                // [4*NPAD]
    uint*     g16u    = (uint*)(partial + 4 * NPAD);      // [NPAD*64] quarter-major
    u16*      esrc    = (u16*)(g16u + NPAD * 64);         // [E] u16
    uint*     H       = (uint*)(esrc + E + (E & 1));      // [BK*CHN]
    uint*     EB      = g16u;                             // [E] alias

    // CSR build: hist -> scans -> scatter -> per-bucket counting sort
    hist_kernel<<<CHN, 256, 0, stream>>>(dst, H, E, CHN);
    colscan_kernel<<<BK, 256, 0, stream>>>(H, T, CHN);
    totscan_kernel<<<1, 256, 0, stream>>>(T, B, row, E, N);
    scatter_kernel<<<CHN, 256, 0, stream>>>(src, dst, H, B, EB, E, CHN);
    bucket_sort_kernel<<<BK, 256, 0, stream>>>(EB, B, row, dinv, esrc, N);

    // w2m / mean(b2)
    w2m_kernel<<<129, 64, 0, stream>>>(W2, b2, w2m);

    // g16 = bf16( dinv * (x @ W1) ) via MFMA, quarter-major (overwrites EB)
    gemm_mfma_kernel<<<(N + 63) / 64, 256, 0, stream>>>(x, W1, g16u, dinv, N);

    // XCD-pinned quarter gather -> partial[q][v]
    gather_q_kernel<<<N, 256, 0, stream>>>(row, esrc, g16u, dinv, b1, w2m, partial, N);

    // mg[v] = dinv[v] * (p0+p1+p2+p3)
    mg_kernel<<<nblocks, 256, 0, stream>>>(partial, dinv, mg, N);

    // out[v] = dinv[v] * (mg[v] + sum mg[nbr]) + mean(b2)
    out_kernel<<<nblocks, 256, 0, stream>>>(row, esrc, mg, dinv, w2m, out, N);
}

// Round 10
// 196.079 us; speedup vs baseline: 1.2845x; 1.2845x over previous
//
#include <hip/hip_runtime.h>
#include <hip/hip_bf16.h>

// GCN: 2x GCNConv(128->128) + LeakyReLU(0.1) + mean over channels.
// N=50000, E=1600000, D=128, fp32 in/out.
//
// R9b: launch-count attack (R9 + macro-hygiene fix: ACC8 param renamed wgt;
//     'w' collided with uint4 member .w). Budget audit (R6-R8): kernels sum
//     to ~130us but totals are 217-252us -> ~70-85us of inter-dispatch gaps
//     over 13 launches. Fused to 6: hist+w2m | colscan+totscan (last-block,
//     atomics+threadfence) | scatter | bucket_sort||gemm (blockIdx branch;
//     race-free because g stores UNSCALED bf16(x@W1) and gather applies
//     dinv[src] per edge via fma) | gather | out.
//     Gather is R7 full-row (64us fetch-bound); R8 quartering cut FETCH
//     208->23.5MB (XCD pinning verified) but 4x wave count -> 104us. Reverted.
// Math (verified R2-R8): h[u]=bf16((x@W1)[u]);
//   mg[u]=dinv[u]*dot(lrelu(dinv[u]*sum_{n in N(u)+u} dinv[n]*h[n] + b1), mean_j W2[:,j]);
//   out[v]=dinv[v]*(mg[v]+sum mg[nbr]) + mean(b2).

#define N_NODES 50000
#define NPAD 50048
#define D 128
#define BK 196           // node buckets: v>>8
#define CHUNK 4096       // edges per stage-1 block

typedef unsigned int uint;
typedef unsigned short u16;
typedef __attribute__((ext_vector_type(8))) short short8;   // 8 bf16 (4 VGPRs)
typedef __attribute__((ext_vector_type(4))) float floatx4;

__device__ __forceinline__ u16 cvt_bf16(float f) {
    uint u = __float_as_uint(f);
    return (u16)((u + 0x7fffu + ((u >> 16) & 1u)) >> 16);   // RNE
}
__device__ __forceinline__ uint pack_bf2(float a, float b) {
    return (uint)cvt_bf16(a) | ((uint)cvt_bf16(b) << 16);
}

// ---------------- K1: per-chunk bucket histogram  +  w2m  +  counter init ----------------
__global__ void hist_w2m_kernel(const int* __restrict__ dst, uint* __restrict__ H,
                                const float* __restrict__ W2, const float* __restrict__ b2,
                                float* __restrict__ w2m, uint* __restrict__ counter,
                                int E, int CHN) {
    int t = threadIdx.x, c = blockIdx.x;
    if (c < CHN) {                         // histogram chunk
        __shared__ uint h[BK];
        if (t < BK) h[t] = 0;
        __syncthreads();
        int e0 = c * CHUNK;
        for (int i = t; i < CHUNK; i += 256) {
            int e = e0 + i;
            if (e < E) atomicAdd(&h[dst[e] >> 8], 1u);
        }
        __syncthreads();
        if (t < BK) H[t * CHN + c] = h[t]; // bucket-major for column scan
    } else {                               // w2m block
        if (t < 128) {
            float s = 0.f;
            for (int j = 0; j < 128; j++) s += W2[t * 128 + j];
            w2m[t] = s * (1.0f / 128.0f);
        } else if (t == 128) {
            float s = 0.f;
            for (int j = 0; j < 128; j++) s += b2[j];
            w2m[128] = s * (1.0f / 128.0f);
        } else if (t == 129) {
            *counter = 0;                  // for K2 last-block detection
        }
    }
}

// ---------------- K2: per-bucket scan over chunks; last block scans totals ----------------
__global__ void scan_kernel(uint* __restrict__ H, uint* __restrict__ T, uint* __restrict__ B,
                            int* __restrict__ row, uint* __restrict__ counter,
                            int CHN, int E, int N) {
    __shared__ uint s[256];
    __shared__ uint ticket_sh;
    int t = threadIdx.x, b = blockIdx.x;
    uint carry = 0;
    for (int base = 0; base < CHN; base += 256) {
        int idx = base + t;
        uint v = (idx < CHN) ? H[b * CHN + idx] : 0u;
        s[t] = v;
        __syncthreads();
#pragma unroll
        for (int off = 1; off < 256; off <<= 1) {
            uint u = (t >= off) ? s[t - off] : 0u;
            __syncthreads();
            s[t] += u;
            __syncthreads();
        }
        if (idx < CHN) H[b * CHN + idx] = carry + s[t] - v;   // exclusive + carry
        carry += s[255];
        __syncthreads();
    }
    if (t == 0) {
        atomicExch(&T[b], carry);          // device-scope store (crosses XCD L2s)
        __threadfence();
        ticket_sh = atomicAdd(counter, 1);
    }
    __syncthreads();
    if (ticket_sh == (uint)(gridDim.x - 1)) {      // last block: scan bucket totals
        __threadfence();
        uint v = (t < BK) ? atomicAdd(&T[t], 0u) : 0u;   // atomic read (coherent)
        s[t] = v;
        __syncthreads();
#pragma unroll
        for (int off = 1; off < 256; off <<= 1) {
            uint u = (t >= off) ? s[t - off] : 0u;
            __syncthreads();
            s[t] += u;
            __syncthreads();
        }
        if (t < BK) B[t] = s[t] - v;
        if (t == 0) { B[BK] = (uint)E; row[N] = E; }
    }
}

// ---------------- K3: scatter edges into bucket regions (LDS cursors) ----------------
__global__ void scatter_kernel(const int* __restrict__ src, const int* __restrict__ dst,
                               const uint* __restrict__ H, const uint* __restrict__ B,
                               uint* __restrict__ EB, int E, int CHN) {
    __shared__ uint cur[BK];
    int t = threadIdx.x, c = blockIdx.x;
    if (t < BK) cur[t] = B[t] + H[t * CHN + c];
    __syncthreads();
    int e0 = c * CHUNK;
    for (int i = t; i < CHUNK; i += 256) {
        int e = e0 + i;
        if (e < E) {
            int d = dst[e];
            uint slot = atomicAdd(&cur[d >> 8], 1u);
            EB[slot] = ((uint)(d & 255) << 16) | (uint)src[e];
        }
    }
}

// ---------------- K4: bucket_sort (blocks 0..BK-1)  ||  MFMA gemm (blocks BK..) ----------------
// Sort: per-bucket counting sort by dst&255 -> esrc, row, dinv (dense writes).
// Gemm: g16[M,128] = bf16( x @ W1 )  -- UNSCALED (dinv applied per-edge in gather),
//       so gemm has no dependence on sort outputs; safe to run concurrently.
#define WT_STRIDE 136
union SortGemmSmem {
    struct { uint cnt[256], s[256], cur[256]; } sort;
    u16 wt[128 * WT_STRIDE];               // 34.8 KB
};
__global__ __launch_bounds__(256) void sortgemm_kernel(
    const uint* __restrict__ EB, const uint* __restrict__ B,
    int* __restrict__ row, float* __restrict__ dinv, u16* __restrict__ esrc,
    const float* __restrict__ A, const float* __restrict__ W,
    uint* __restrict__ G32, int N, int M) {
    __shared__ SortGemmSmem sm;
    int t = threadIdx.x;

    if (blockIdx.x < BK) {                 // ---- bucket sort ----
        int b = blockIdx.x;
        uint base = B[b], ne = B[b + 1] - base;
        sm.sort.cnt[t] = 0;
        __syncthreads();
        for (uint i = t; i < ne; i += 256) atomicAdd(&sm.sort.cnt[EB[base + i] >> 16], 1u);
        __syncthreads();
        uint c = sm.sort.cnt[t];
        sm.sort.s[t] = c;
        __syncthreads();
#pragma unroll
        for (int off = 1; off < 256; off <<= 1) {
            uint u = (t >= off) ? sm.sort.s[t - off] : 0u;
            __syncthreads();
            sm.sort.s[t] += u;
            __syncthreads();
        }
        uint p = sm.sort.s[t] - c;          // exclusive prefix within bucket
        int v = (b << 8) + t;
        if (v < N) {
            row[v] = (int)(base + p);
            dinv[v] = rsqrtf((float)(c + 1u));   // +1 self-loop
        }
        sm.sort.cur[t] = base + p;
        __syncthreads();
        for (uint i = t; i < ne; i += 256) {
            uint u = EB[base + i];
            uint slot = atomicAdd(&sm.sort.cur[u >> 16], 1u);
            esrc[slot] = (u16)(u & 0xffffu);
        }
    } else {                               // ---- MFMA gemm ----
        int bid = blockIdx.x - BK;
        for (int i = t; i < 128 * 128; i += 256) {   // stage W1^T as bf16
            int k = i >> 7, n = i & 127;
            sm.wt[n * WT_STRIDE + k] = cvt_bf16(W[i]);
        }
        __syncthreads();

        int wave = t >> 6, lane = t & 63;
        int m = lane & 15, quad = lane >> 4;
        int rowa = bid * 64 + wave * 16 + m;
        int rowc = rowa < M ? rowa : M - 1;
        const float* Arow = A + (long)rowc * D;

        short8 afrag[4];
#pragma unroll
        for (int kt = 0; kt < 4; kt++) {
            int k0 = kt * 32 + quad * 8;
            float4 f0 = *(const float4*)(Arow + k0);
            float4 f1 = *(const float4*)(Arow + k0 + 4);
            short8 af;
            af[0] = (short)cvt_bf16(f0.x); af[1] = (short)cvt_bf16(f0.y);
            af[2] = (short)cvt_bf16(f0.z); af[3] = (short)cvt_bf16(f0.w);
            af[4] = (short)cvt_bf16(f1.x); af[5] = (short)cvt_bf16(f1.y);
            af[6] = (short)cvt_bf16(f1.z); af[7] = (short)cvt_bf16(f1.w);
            afrag[kt] = af;
        }

        int orow0 = bid * 64 + wave * 16;
        for (int n0 = 0; n0 < 128; n0 += 16) {
            floatx4 acc = {0.f, 0.f, 0.f, 0.f};
#pragma unroll
            for (int kt = 0; kt < 4; kt++) {
                short8 bf = *(const short8*)(sm.wt + (n0 + m) * WT_STRIDE + kt * 32 + quad * 8);
                acc = __builtin_amdgcn_mfma_f32_16x16x32_bf16(afrag[kt], bf, acc, 0, 0, 0);
            }
#pragma unroll
            for (int r = 0; r < 4; r++) {
                float val = acc[r];
                float oth = __shfl_xor(val, 1, 64);      // partner column
                int orow = orow0 + quad * 4 + r;
                if (orow < M && (m & 1) == 0)
                    G32[(long)orow * 64 + ((n0 + m) >> 1)] = pack_bf2(val, oth);
            }
        }
    }
}

// ---------------- K5: fused gather(bf16, dinv-fma) + leakyrelu + dot(w2m) ----------------
// R7 structure: one wave/node; 8 chains x 8 lanes; 2 uint4/edge, 2-deep pipeline.
// dinv[src] applied per edge via fma (g is unscaled).
__global__ __launch_bounds__(256) void gather_node_kernel(
    const int* __restrict__ row, const u16* __restrict__ esrc,
    const uint* __restrict__ g16, const float* __restrict__ dinv,
    const float* __restrict__ b1, const float* __restrict__ w2m,
    float* __restrict__ mg, int N) {
    int wave = threadIdx.x >> 6;
    int lane = threadIdx.x & 63;
    int sub = lane & 7;        // 16-channel slice: uint4 pair 2*sub, 2*sub+1
    int nb = lane >> 3;        // 8 neighbor chains
    int v = blockIdx.x * 4 + wave;
    if (v >= N) return;

    const uint4* gv = (const uint4*)g16;   // 16 uint4 per 256B row
    float dvv = dinv[v];
    float acc[16];
#pragma unroll
    for (int i = 0; i < 16; i++) acc[i] = 0.f;

#define ACC8(ua, ub, wgt) {                                              \
    uint uu[8] = {(ua).x, (ua).y, (ua).z, (ua).w, (ub).x, (ub).y, (ub).z, (ub).w}; \
    _Pragma("unroll")                                                    \
    for (int i = 0; i < 8; i++) {                                        \
        acc[2*i]   += (wgt) * __uint_as_float(uu[i] << 16);              \
        acc[2*i+1] += (wgt) * __uint_as_float(uu[i] & 0xffff0000u);      \
    } }

    if (nb == 0) {             // self-loop term: dinv[v]*h[v]
        long rb = (long)v * 16 + 2 * sub;
        uint4 ua = gv[rb], ub = gv[rb + 1];
        ACC8(ua, ub, dvv)
    }
    int jb = row[v], je = row[v + 1];
    int j = jb + nb;
    if (j < je) {              // 2-deep pipeline per chain
        int s0 = esrc[j];
        float wA = dinv[s0];
        long r0 = (long)s0 * 16 + 2 * sub;
        uint4 p0 = gv[r0], p1 = gv[r0 + 1];
        j += 8;
        while (j < je) {
            int s1 = esrc[j];
            float wB = dinv[s1];
            long r1 = (long)s1 * 16 + 2 * sub;
            uint4 q0 = gv[r1], q1 = gv[r1 + 1];
            j += 8;
            ACC8(p0, p1, wA)
            p0 = q0; p1 = q1; wA = wB;
        }
        ACC8(p0, p1, wA)
    }
#undef ACC8

    // reduce the 8 chains
#pragma unroll
    for (int i = 0; i < 16; i++) {
        acc[i] += __shfl_xor(acc[i], 8, 64);
        acc[i] += __shfl_xor(acc[i], 16, 64);
        acc[i] += __shfl_xor(acc[i], 32, 64);
    }

    if (nb == 0) {             // lane sub holds channels 16*sub .. 16*sub+15
        const float4* bp = (const float4*)b1;
        const float4* wp = (const float4*)w2m;
        float s = 0.f;
#pragma unroll
        for (int q4 = 0; q4 < 4; q4++) {
            float4 bb = bp[sub * 4 + q4];
            float4 wm = wp[sub * 4 + q4];
            float t0 = dvv * acc[4*q4 + 0] + bb.x; t0 = t0 >= 0.f ? t0 : 0.1f * t0;
            float t1 = dvv * acc[4*q4 + 1] + bb.y; t1 = t1 >= 0.f ? t1 : 0.1f * t1;
            float t2 = dvv * acc[4*q4 + 2] + bb.z; t2 = t2 >= 0.f ? t2 : 0.1f * t2;
            float t3 = dvv * acc[4*q4 + 3] + bb.w; t3 = t3 >= 0.f ? t3 : 0.1f * t3;
            s += t0 * wm.x + t1 * wm.y + t2 * wm.z + t3 * wm.w;
        }
        s += __shfl_xor(s, 1, 64);
        s += __shfl_xor(s, 2, 64);
        s += __shfl_xor(s, 4, 64);
        if (sub == 0) mg[v] = dvv * s;
    }
}

// ---------------- K6: scalar aggregate for conv2 + mean ----------------
__global__ void out_kernel(const int* __restrict__ row, const u16* __restrict__ esrc,
                           const float* __restrict__ mg, const float* __restrict__ dinv,
                           const float* __restrict__ w2m, float* __restrict__ out, int N) {
    int v = blockIdx.x * blockDim.x + threadIdx.x;
    if (v >= N) return;
    float acc = mg[v];
    int jb = row[v], je = row[v + 1];
    int j = jb;
    for (; j + 8 <= je; j += 8) {
        acc += mg[esrc[j]] + mg[esrc[j + 1]] + mg[esrc[j + 2]] + mg[esrc[j + 3]] +
               mg[esrc[j + 4]] + mg[esrc[j + 5]] + mg[esrc[j + 6]] + mg[esrc[j + 7]];
    }
    for (; j < je; j++) acc += mg[esrc[j]];
    out[v] = dinv[v] * acc + w2m[128];
}

extern "C" void kernel_launch(void* const* d_in, const int* in_sizes, int n_in,
                              void* d_out, int out_size, void* d_ws, size_t ws_size,
                              hipStream_t stream) {
    const float* x  = (const float*)d_in[0];
    const int* ei   = (const int*)d_in[1];
    const float* W1 = (const float*)d_in[2];
    const float* b1 = (const float*)d_in[3];
    const float* W2 = (const float*)d_in[4];
    const float* b2 = (const float*)d_in[5];
    float* out = (float*)d_out;

    const int N = N_NODES;
    const int E = in_sizes[1] / 2;
    const int* src = ei;
    const int* dst = ei + E;
    const int CHN = (E + CHUNK - 1) / CHUNK;   // 391
    const int nblocks = (N + 255) / 256;       // 196

    // workspace (4B units). EB is NOT aliased with g16 (sort runs || gemm in K4).
    float*    dinv    = (float*)d_ws;                     // [NPAD]
    int*      row     = (int*)(dinv + NPAD);              // [NPAD+16]
    uint*     B       = (uint*)(row + NPAD + 16);         // [256] (BK+1 used)
    float*    w2m     = (float*)(B + 256);                // [256] ([128]=mean b2)
    float*    mg      = w2m + 256;                        // [NPAD]
    uint*     T       = (uint*)(mg + NPAD);               // [256]
    uint*     counter = T + 256;                          // [16]
    uint*     g16u    = counter + 16;                     // [NPAD*64] (16B aligned)
    u16*      esrc    = (u16*)(g16u + (long)NPAD * 64);   // [E] u16
    uint*     H       = (uint*)(esrc + E);                // [BK*CHN]
    uint*     EB      = H + BK * CHN;                     // [E]

    // K1: histogram chunks + w2m + counter init
    hist_w2m_kernel<<<CHN + 1, 256, 0, stream>>>(dst, H, W2, b2, w2m, counter, E, CHN);
    // K2: per-bucket chunk scan; last block produces B[] and row[N]
    scan_kernel<<<BK, 256, 0, stream>>>(H, T, B, row, counter, CHN, E, N);
    // K3: scatter into bucket regions
    scatter_kernel<<<CHN, 256, 0, stream>>>(src, dst, H, B, EB, E, CHN);
    // K4: bucket sort (196 blocks) || MFMA gemm (782 blocks)
    sortgemm_kernel<<<BK + (N + 63) / 64, 256, 0, stream>>>(EB, B, row, dinv, esrc,
                                                            x, W1, g16u, N, N);
    // K5: gather + lrelu + dot -> mg
    gather_node_kernel<<<(N + 3) / 4, 256, 0, stream>>>(row, esrc, g16u, dinv, b1, w2m, mg, N);
    // K6: scalar aggregate + mean -> out
    out_kernel<<<nblocks, 256, 0, stream>>>(row, esrc, mg, dinv, w2m, out, N);
}